// Round 1
// baseline (386.735 us; speedup 1.0000x reference)
//
#include <hip/hip_runtime.h>

#define EMBED   256
#define NGRAPH  256
#define P       4                    // partial-sum blocks per graph (no atomics)
#define BLOCK1  512
#define NW1     (BLOCK1 / 64)        // 8 waves / block
#define WPG     (P * NW1)            // 32 waves cooperating on one graph
#define BLOCK3  256
#define NB3     2048                 // broadcast grid: 8 blocks/CU

typedef float f32x4 __attribute__((ext_vector_type(4)));

// ---------------------------------------------------------------------------
// K1: partial segment sums. Block (g,p) sums a strided share of graph g's
// rows (batch sorted -> contiguous range via binary search). 1024 blocks
// of 8 waves = 32 waves/CU (vs 8 before): full-occupancy streaming read.
// ---------------------------------------------------------------------------
__global__ __launch_bounds__(BLOCK1, 8) void seg_partial(
    const float* __restrict__ x, const int* __restrict__ batch,
    float* __restrict__ partial, int nNodes) {
  const int g  = blockIdx.x >> 2;          // P == 4
  const int p  = blockIdx.x & (P - 1);
  const int t  = threadIdx.x;
  const int q  = t >> 6;                   // wave in block
  const int c4 = t & 63;                   // float4 column

  int n0, n1;
  { int a = 0, b = nNodes;
    while (a < b) { int m = (a + b) >> 1; (batch[m] < g) ? (a = m + 1) : (b = m); }
    n0 = a; }
  { int a = n0, b = nNodes;
    while (a < b) { int m = (a + b) >> 1; (batch[m] <= g) ? (a = m + 1) : (b = m); }
    n1 = a; }
  const int cnt = n1 - n0;

  const float4* xp = (const float4*)x + (size_t)n0 * (EMBED / 4) + c4;
  const int w = p * NW1 + q;               // 0..31: this wave's slot in the graph
  float4 a0 = make_float4(0.f, 0.f, 0.f, 0.f);
  float4 a1 = make_float4(0.f, 0.f, 0.f, 0.f);
  int i = w;
  for (; i + 7 * WPG < cnt; i += 8 * WPG) {
    float4 v0 = xp[(size_t)(i          ) * (EMBED / 4)];
    float4 v1 = xp[(size_t)(i + 1 * WPG) * (EMBED / 4)];
    float4 v2 = xp[(size_t)(i + 2 * WPG) * (EMBED / 4)];
    float4 v3 = xp[(size_t)(i + 3 * WPG) * (EMBED / 4)];
    float4 v4 = xp[(size_t)(i + 4 * WPG) * (EMBED / 4)];
    float4 v5 = xp[(size_t)(i + 5 * WPG) * (EMBED / 4)];
    float4 v6 = xp[(size_t)(i + 6 * WPG) * (EMBED / 4)];
    float4 v7 = xp[(size_t)(i + 7 * WPG) * (EMBED / 4)];
    a0.x += v0.x + v1.x; a0.y += v0.y + v1.y; a0.z += v0.z + v1.z; a0.w += v0.w + v1.w;
    a1.x += v2.x + v3.x; a1.y += v2.y + v3.y; a1.z += v2.z + v3.z; a1.w += v2.w + v3.w;
    a0.x += v4.x + v5.x; a0.y += v4.y + v5.y; a0.z += v4.z + v5.z; a0.w += v4.w + v5.w;
    a1.x += v6.x + v7.x; a1.y += v6.y + v7.y; a1.z += v6.z + v7.z; a1.w += v6.w + v7.w;
  }
  for (; i < cnt; i += WPG) {
    float4 v = xp[(size_t)i * (EMBED / 4)];
    a0.x += v.x; a0.y += v.y; a0.z += v.z; a0.w += v.w;
  }
  a0.x += a1.x; a0.y += a1.y; a0.z += a1.z; a0.w += a1.w;

  __shared__ float4 red4[NW1][EMBED / 4];  // == float [NW1][EMBED]
  red4[q][c4] = a0;
  __syncthreads();
  if (t < EMBED) {
    const float* rf = (const float*)red4;
    float s = 0.f;
#pragma unroll
    for (int k = 0; k < NW1; ++k) s += rf[k * EMBED + t];
    partial[((size_t)p * NGRAPH + g) * EMBED + t] = s;
  }
}

// ---------------------------------------------------------------------------
// K2: reduce the P partials, mean, two 256x256 matvecs -> rows[g][:].
// 256 blocks x 256 threads; weights are L2-hot. ~4 us.
// ---------------------------------------------------------------------------
__global__ __launch_bounds__(EMBED, 1) void graph_rows(
    const float* __restrict__ partial, const int* __restrict__ batch,
    const float* __restrict__ in_w, const float* __restrict__ in_b,
    const float* __restrict__ out_w, const float* __restrict__ out_b,
    float* __restrict__ rows, int nNodes) {
  const int g = blockIdx.x;
  const int t = threadIdx.x;

  int n0, n1;
  { int a = 0, b = nNodes;
    while (a < b) { int m = (a + b) >> 1; (batch[m] < g) ? (a = m + 1) : (b = m); }
    n0 = a; }
  { int a = n0, b = nNodes;
    while (a < b) { int m = (a + b) >> 1; (batch[m] <= g) ? (a = m + 1) : (b = m); }
    n1 = a; }
  const float inv = 1.0f / fmaxf((float)(n1 - n0), 1.0f);

  __shared__ float sg[EMBED];
  __shared__ float sv[EMBED];

  float s = 0.f;
#pragma unroll
  for (int p = 0; p < P; ++p) s += partial[((size_t)p * NGRAPH + g) * EMBED + t];
  sg[t] = s * inv;
  __syncthreads();

  float acc = in_b[2 * EMBED + t];
  const float4* wrow = (const float4*)(in_w + (size_t)(2 * EMBED + t) * EMBED);
#pragma unroll 8
  for (int k4 = 0; k4 < EMBED / 4; ++k4) {
    const float4 w = wrow[k4];
    const int k = k4 * 4;
    acc += sg[k] * w.x + sg[k + 1] * w.y + sg[k + 2] * w.z + sg[k + 3] * w.w;
  }
  sv[t] = acc;
  __syncthreads();

  float acc2 = out_b[t];
  const float4* wrow2 = (const float4*)(out_w + (size_t)t * EMBED);
#pragma unroll 8
  for (int k4 = 0; k4 < EMBED / 4; ++k4) {
    const float4 w = wrow2[k4];
    const int k = k4 * 4;
    acc2 += sv[k] * w.x + sv[k + 1] * w.y + sv[k + 2] * w.z + sv[k + 3] * w.w;
  }
  rows[(size_t)g * EMBED + t] = acc2;
}

// ---------------------------------------------------------------------------
// K3: out[n][:] = rows[batch[n]][:]. Grid-stride over node-float4s, fully
// coalesced 1 KB/wave stores. Nontemporal stores keep x resident in L3.
// batch[n] is wave-uniform (64 consecutive float4 = one row).
// ---------------------------------------------------------------------------
__global__ __launch_bounds__(BLOCK3, 8) void bcast(
    const float4* __restrict__ rows4, const int* __restrict__ batch,
    float4* __restrict__ out4, long long total) {
  const long long stride = (long long)gridDim.x * BLOCK3;
  long long i = (long long)blockIdx.x * BLOCK3 + threadIdx.x;
  for (; i + 3 * stride < total; i += 4 * stride) {
    const long long i0 = i, i1 = i + stride, i2 = i + 2 * stride, i3 = i + 3 * stride;
    const int g0 = batch[(int)(i0 >> 6)];
    const int g1 = batch[(int)(i1 >> 6)];
    const int g2 = batch[(int)(i2 >> 6)];
    const int g3 = batch[(int)(i3 >> 6)];
    const float4 r0 = rows4[(g0 << 6) + (int)(i0 & 63)];
    const float4 r1 = rows4[(g1 << 6) + (int)(i1 & 63)];
    const float4 r2 = rows4[(g2 << 6) + (int)(i2 & 63)];
    const float4 r3 = rows4[(g3 << 6) + (int)(i3 & 63)];
    __builtin_nontemporal_store(*(const f32x4*)&r0, (f32x4*)(out4 + i0));
    __builtin_nontemporal_store(*(const f32x4*)&r1, (f32x4*)(out4 + i1));
    __builtin_nontemporal_store(*(const f32x4*)&r2, (f32x4*)(out4 + i2));
    __builtin_nontemporal_store(*(const f32x4*)&r3, (f32x4*)(out4 + i3));
  }
  for (; i < total; i += stride) {
    const int gg = batch[(int)(i >> 6)];
    const float4 r = rows4[(gg << 6) + (int)(i & 63)];
    __builtin_nontemporal_store(*(const f32x4*)&r, (f32x4*)(out4 + i));
  }
}

extern "C" void kernel_launch(void* const* d_in, const int* in_sizes, int n_in,
                              void* d_out, int out_size, void* d_ws, size_t ws_size,
                              hipStream_t stream) {
  const float* x     = (const float*)d_in[0];
  const float* in_w  = (const float*)d_in[1];
  const float* in_b  = (const float*)d_in[2];
  const float* out_w = (const float*)d_in[3];
  const float* out_b = (const float*)d_in[4];
  const int*   batch = (const int*)d_in[5];
  const int nNodes = in_sizes[5];

  const size_t needR = (size_t)NGRAPH * EMBED * sizeof(float);          // 256 KB
  const size_t needP = (size_t)P * NGRAPH * EMBED * sizeof(float);      // 1 MB

  float* rows = (float*)d_ws;
  float* partial;
  if (ws_size >= needR + needP) {
    partial = rows + (size_t)NGRAPH * EMBED;
  } else {
    // d_out as scratch: written by K1, consumed by K2, then fully
    // overwritten by K3 (stream-ordered, no race).
    partial = (float*)d_out;
  }

  seg_partial<<<NGRAPH * P, BLOCK1, 0, stream>>>(x, batch, partial, nNodes);
  graph_rows<<<NGRAPH, EMBED, 0, stream>>>(partial, batch, in_w, in_b,
                                           out_w, out_b, rows, nNodes);
  const long long total = (long long)nNodes * (EMBED / 4);
  bcast<<<NB3, BLOCK3, 0, stream>>>((const float4*)rows, batch,
                                    (float4*)d_out, total);
}